// Round 8
// baseline (726.204 us; speedup 1.0000x reference)
//
#include <hip/hip_runtime.h>
#include <math.h>

#define NB 16
#define SL 2048
#define HD 64
#define TQ 16
#define BK 64
#define NT (SL / BK)          // 32 k-tiles
#define SC2 0.18033688f       // (1/TEMPERATURE) * log2(e): exp(s/8) = exp2(s*SC2)
#define SSTRIDE 2056          // fp16 elems per S row (2048 + 8 pad, 16B-aligned rows)

typedef _Float16 half8 __attribute__((ext_vector_type(8)));
typedef float floatx4 __attribute__((ext_vector_type(4)));
typedef int intx4 __attribute__((ext_vector_type(4)));

__device__ __forceinline__ half8 load_frag_f32(const float* p) {
  floatx4 f0 = *(const floatx4*)p;
  floatx4 f1 = *(const floatx4*)(p + 4);
  half8 h;
  h[0] = (_Float16)f0[0]; h[1] = (_Float16)f0[1];
  h[2] = (_Float16)f0[2]; h[3] = (_Float16)f0[3];
  h[4] = (_Float16)f1[0]; h[5] = (_Float16)f1[1];
  h[6] = (_Float16)f1[2]; h[7] = (_Float16)f1[3];
  return h;
}

// Fused pre-pass, 256 threads/block (at the mask stream's BW floor ~6.2 TB/s).
// bid < 512  : prep — K -> KH (f16), V -> VT (f16 transposed [b][d][k]).
// bid >= 512 : pack — reads DM+MMk (537 MB), keep = dm & ~mk, bit-packed to BITS
//              (8 MiB, L2/L3-resident for the attn kernel).
__global__ __launch_bounds__(256) void prep_pack_kernel(
    const float* __restrict__ K, const float* __restrict__ V,
    const int* __restrict__ DM, const int* __restrict__ MMk,
    _Float16* __restrict__ KH, _Float16* __restrict__ VT,
    unsigned char* __restrict__ BITS)
{
  const int bid = blockIdx.x;
  const int t   = (int)threadIdx.x;

  if (bid >= 512) {
    const size_t r0 = (size_t)(bid - 512) * 16;
    #pragma unroll 4
    for (int r = 0; r < 16; ++r) {
      const size_t off = (r0 + r) * SL + (size_t)t * 8;
      intx4 d0 = __builtin_nontemporal_load((const intx4*)(DM + off));
      intx4 d1 = __builtin_nontemporal_load((const intx4*)(DM + off + 4));
      intx4 m0 = __builtin_nontemporal_load((const intx4*)(MMk + off));
      intx4 m1 = __builtin_nontemporal_load((const intx4*)(MMk + off + 4));
      unsigned byte = 0;
      #pragma unroll
      for (int j = 0; j < 4; ++j) {
        byte |= (unsigned)((d0[j] & ~m0[j]) & 1) << j;
        byte |= (unsigned)((d1[j] & ~m1[j]) & 1) << (j + 4);
      }
      BITS[(r0 + r) * (SL / 8) + t] = (unsigned char)byte;
    }
    return;
  }

  __shared__ __align__(16) _Float16 tile[64][72];   // V tile, 16-chunk XOR swizzle
  const int k0 = (bid & 31) * 64;
  const int b  = bid >> 5;
  const size_t base = (size_t)b * SL * HD;
  const int r  = t >> 2;
  const int cq = (t & 3) * 16;

  const float* kp = K + base + (size_t)(k0 + r) * HD + cq;
  const float* vp = V + base + (size_t)(k0 + r) * HD + cq;
  half8 kh0 = load_frag_f32(kp), kh1 = load_frag_f32(kp + 8);
  half8 vh0 = load_frag_f32(vp), vh1 = load_frag_f32(vp + 8);

  _Float16* khp = KH + base + (size_t)(k0 + r) * HD + cq;
  *(half8*)khp       = kh0;
  *(half8*)(khp + 8) = kh1;

  const int wc = cq ^ (((r >> 4) & 3) * 16);
  *(half8*)&tile[r][wc]     = vh0;
  *(half8*)&tile[r][wc + 8] = vh1;
  __syncthreads();

  const int sx = ((cq >> 4) & 3) * 16;
  half8 o0, o1;
  #pragma unroll
  for (int i = 0; i < 8; ++i) {
    o0[i] = tile[cq + i][r ^ sx];
    o1[i] = tile[cq + 8 + i][r ^ sx];
  }
  _Float16* vt = VT + (size_t)b * HD * SL + (size_t)r * SL + k0 + cq;
  *(half8*)vt       = o0;
  *(half8*)(vt + 8) = o1;
}

// One block = 16 q-rows of one batch, 512 threads = 8 waves, 2 blocks/CU.
// Round-8 = EXACT round-2 kernel (best measured, 696us) + batch-clustered XCD
// swizzle: grid is 1-D 2048; lin -> xcd = lin&7, slot = lin>>3, b = 2*xcd +
// (slot>>7), qt = slot&127. Under round-robin block->XCD dispatch, each XCD
// processes only 2 batches in qt-order, so its concurrent KH/VT working set is
// ~512 KB-1 MB << 4 MB L2. Theory (R5+R7 evidence): attn is bound by ~1 GB of
// L3->L2 re-reads of KH/VT (Attn write stream evicts them from L2); clustering
// makes them L2-resident. R5: 2x blocks -> 2x traffic -> 2x time. R7: deeper
// MLP, same traffic -> no gain.
// MODE 2: KH/VT + BITS. MODE 1: KH/VT, masks from global. MODE 0: no workspace.
template <int MODE>
__global__ __launch_bounds__(512, 4) void attn_kernel(
    const float* __restrict__ Q, const float* __restrict__ K,
    const float* __restrict__ V, const _Float16* __restrict__ KH,
    const _Float16* __restrict__ VT, const unsigned char* __restrict__ BITS,
    const int* __restrict__ DM, const int* __restrict__ MMk,
    float* __restrict__ Out, float* __restrict__ Attn)
{
  // ---- batch-clustered XCD swizzle (1-D grid, 2048 blocks) ----
  const int lin  = (int)blockIdx.x;
  const int xcd  = lin & 7;
  const int slot = lin >> 3;             // 0..255 per XCD
  const int b    = xcd * 2 + (slot >> 7);
  const int qt   = slot & 127;

  const int tid   = (int)threadIdx.x;
  const int w     = tid >> 6;
  const int w4    = w & 3;
  const int hf    = w >> 2;
  const int lane  = tid & 63;
  const int quad  = lane >> 4;
  const int nl    = lane & 15;
  const int row16 = tid >> 5;
  const int ci    = tid & 31;

  const int qbase    = qt * TQ;
  const size_t bLD   = (size_t)b * SL * HD;
  const size_t mbase = ((size_t)b * SL + qbase) * SL;

  __shared__ __align__(16) _Float16 S[TQ * SSTRIDE];   // 65.8 KB
  __shared__ float sinv_s[TQ];
  __shared__ float obuf[TQ][65];

  // ---- mask bits: one u64 per thread covers 64 cols of its row (tid = row16*32+ci)
  unsigned Wlo = 0, Whi = 0;
  if constexpr (MODE == 2) {
    const unsigned long long* browp =
        (const unsigned long long*)BITS + ((size_t)b * SL + qbase) * (SL / 64);
    const unsigned long long Wll = browp[tid];
    Wlo = (unsigned)Wll;
    Whi = (unsigned)(Wll >> 32);
  }

  // ---- Q fragments (A operand): lane holds Q[qbase + nl][quad*8+j (+32)]
  half8 aq0, aq1;
  {
    const float* qp = Q + bLD + (size_t)(qbase + nl) * HD + quad * 8;
    aq0 = load_frag_f32(qp);
    aq1 = load_frag_f32(qp + 32);
  }

  // ================= Phase A: QK^T -> S (each wave: 16 tiles) =================
  const int kt0 = hf * (NT / 2);
  #pragma unroll 2
  for (int kti = 0; kti < NT / 2; ++kti) {
    const int kt = kt0 + kti;
    half8 bk0, bk1;
    if constexpr (MODE >= 1) {
      const _Float16* kp = KH + bLD + (size_t)(kt * BK + w4 * 16 + nl) * HD + quad * 8;
      bk0 = *(const half8*)kp;
      bk1 = *(const half8*)(kp + 32);
    } else {
      const float* kp = K + bLD + (size_t)(kt * BK + w4 * 16 + nl) * HD + quad * 8;
      bk0 = load_frag_f32(kp);
      bk1 = load_frag_f32(kp + 32);
    }
    floatx4 acc = {0.f, 0.f, 0.f, 0.f};
    acc = __builtin_amdgcn_mfma_f32_16x16x32_f16(aq0, bk0, acc, 0, 0, 0);
    acc = __builtin_amdgcn_mfma_f32_16x16x32_f16(aq1, bk1, acc, 0, 0, 0);
    const int col = kt * BK + w4 * 16 + nl;
    #pragma unroll
    for (int r = 0; r < 4; ++r)
      S[(quad * 4 + r) * SSTRIDE + col] = (_Float16)(acc[r] * SC2);
  }
  __syncthreads();

  // ========== P1: mask + exp2 + sum, one in-place pass ==========
  _Float16* srow = &S[row16 * SSTRIDE];
  float sum = 0.f;
  if constexpr (MODE == 2) {
    const bool useLo = (ci & 4) == 0;        // byte (ci&7) lives in lo word if <4
    const int  bsh   = (ci & 3) * 8;
    #pragma unroll
    for (int it = 0; it < 8; ++it) {
      const int c    = it * 256 + ci * 8;
      const int srcl = (lane & 32) | (it * 4 + (ci >> 3));
      const unsigned lo = __shfl(Wlo, srcl, 64);
      const unsigned hi = __shfl(Whi, srcl, 64);
      const unsigned kb = ((useLo ? lo : hi) >> bsh) & 0xFFu;
      half8 s8 = *(const half8*)(srow + c);
      half8 e8;
      #pragma unroll
      for (int j = 0; j < 4; ++j) {
        const float e0 = (kb & (1u << j))       ? __builtin_amdgcn_exp2f((float)s8[j])     : 0.f;
        const float e1 = (kb & (1u << (j + 4))) ? __builtin_amdgcn_exp2f((float)s8[j + 4]) : 0.f;
        sum += e0 + e1;
        e8[j]     = (_Float16)e0;   // e <= ~e^6, fp16 safe (validated earlier rounds)
        e8[j + 4] = (_Float16)e1;
      }
      *(half8*)(srow + c) = e8;     // unnormalized e for PV
    }
  } else {
    const int* dmr = DM  + mbase + (size_t)row16 * SL;
    const int* mkr = MMk + mbase + (size_t)row16 * SL;
    #pragma unroll 4
    for (int it = 0; it < 8; ++it) {
      const int c = it * 256 + ci * 8;
      intx4 d0 = __builtin_nontemporal_load((const intx4*)(dmr + c));
      intx4 d1 = __builtin_nontemporal_load((const intx4*)(dmr + c + 4));
      intx4 m0 = __builtin_nontemporal_load((const intx4*)(mkr + c));
      intx4 m1 = __builtin_nontemporal_load((const intx4*)(mkr + c + 4));
      half8 s8 = *(const half8*)(srow + c);
      half8 e8;
      #pragma unroll
      for (int j = 0; j < 4; ++j) {
        const int keep0 = d0[j] & ~m0[j];
        const int keep1 = d1[j] & ~m1[j];
        const float e0 = keep0 ? __builtin_amdgcn_exp2f((float)s8[j])     : 0.f;
        const float e1 = keep1 ? __builtin_amdgcn_exp2f((float)s8[j + 4]) : 0.f;
        sum += e0 + e1;
        e8[j]     = (_Float16)e0;
        e8[j + 4] = (_Float16)e1;
      }
      *(half8*)(srow + c) = e8;
    }
  }
  #pragma unroll
  for (int off = 1; off < 32; off <<= 1)
    sum += __shfl_xor(sum, off, 64);   // 32 chunk-lanes of this row
  const float is = (sum > 0.f) ? 1.f / sum : 0.f;
  if (ci == 0) sinv_s[row16] = is;
  __syncthreads();   // all e in S + sinv_s visible before PV

  // ===== PV MFMA (16 tiles/wave) with interleaved normalized attn stores =====
  const float isr = sinv_s[row16];
  float* arow = Attn + mbase + (size_t)row16 * SL;
  floatx4 oacc = {0.f, 0.f, 0.f, 0.f};
  #pragma unroll
  for (int kti = 0; kti < NT / 2; ++kti) {
    const int kt = kt0 + kti;
    // A operand: lane holds E[m = nl][k = kt*64 + quad*8 + j (+32)]
    half8 ap0 = *(const half8*)(&S[nl * SSTRIDE + kt * BK + quad * 8]);
    half8 ap1 = *(const half8*)(&S[nl * SSTRIDE + kt * BK + quad * 8 + 32]);
    // B operand: lane holds V[k = kt*64 + quad*8 + j (+32)][n = w4*16 + nl]
    half8 bv0, bv1;
    if constexpr (MODE >= 1) {
      const _Float16* vp = VT + bLD + (size_t)(w4 * 16 + nl) * SL + kt * BK + quad * 8;
      bv0 = *(const half8*)vp;
      bv1 = *(const half8*)(vp + 32);
    } else {
      const float* vp = V + bLD + (size_t)(kt * BK + quad * 8) * HD + w4 * 16 + nl;
      #pragma unroll
      for (int j = 0; j < 8; ++j) {
        bv0[j] = (_Float16)vp[(size_t)j * HD];
        bv1[j] = (_Float16)vp[(size_t)(j + 32) * HD];
      }
    }
    oacc = __builtin_amdgcn_mfma_f32_16x16x32_f16(ap0, bv0, oacc, 0, 0, 0);
    oacc = __builtin_amdgcn_mfma_f32_16x16x32_f16(ap1, bv1, oacc, 0, 0, 0);
    // P3 chunk every other tile: stores drain under the MFMA latency
    if ((kti & 1) == 0) {
      const int c = (kti >> 1) * 256 + ci * 8;
      half8 e8v = *(const half8*)(srow + c);
      floatx4 o0, o1;
      #pragma unroll
      for (int j = 0; j < 4; ++j) {
        o0[j] = (float)e8v[j]     * isr;
        o1[j] = (float)e8v[j + 4] * isr;
      }
      __builtin_nontemporal_store(o0, (floatx4*)(arow + c));
      __builtin_nontemporal_store(o1, (floatx4*)(arow + c + 4));
    }
  }

  // ---- merge the two k-halves, normalize, store O
  if (hf == 1) {
    #pragma unroll
    for (int r = 0; r < 4; ++r)
      obuf[quad * 4 + r][w4 * 16 + nl] = oacc[r];
  }
  __syncthreads();
  if (hf == 0) {
    float* op = Out + ((size_t)b * SL + qbase) * HD;
    #pragma unroll
    for (int r = 0; r < 4; ++r) {
      const int row = quad * 4 + r;
      op[(size_t)row * HD + w4 * 16 + nl] =
          (oacc[r] + obuf[row][w4 * 16 + nl]) * sinv_s[row];
    }
  }
}

extern "C" void kernel_launch(void* const* d_in, const int* in_sizes, int n_in,
                              void* d_out, int out_size, void* d_ws, size_t ws_size,
                              hipStream_t stream) {
  const float* Q  = (const float*)d_in[0];
  const float* K  = (const float*)d_in[1];
  const float* V  = (const float*)d_in[2];
  const int* DM   = (const int*)d_in[3];
  const int* MMk  = (const int*)d_in[4];
  float* Out  = (float*)d_out;
  float* Attn = (float*)d_out + (size_t)NB * SL * HD;
  dim3 grid((SL / TQ) * NB);   // 1-D, 2048 blocks; swizzle decoded in-kernel

  const size_t needKV   = (size_t)2 * NB * SL * HD * sizeof(_Float16);  // 8 MiB
  const size_t needBits = (size_t)NB * SL * (SL / 8);                   // 8 MiB
  if (d_ws != nullptr && ws_size >= needKV + needBits) {
    _Float16* KH = (_Float16*)d_ws;
    _Float16* VT = KH + (size_t)NB * SL * HD;
    unsigned char* BITS = (unsigned char*)(VT + (size_t)NB * SL * HD);
    prep_pack_kernel<<<dim3(512 + 2048), 256, 0, stream>>>(K, V, DM, MMk, KH, VT, BITS);
    attn_kernel<2><<<grid, 512, 0, stream>>>(Q, K, V, KH, VT, BITS, DM, MMk, Out, Attn);
  } else if (d_ws != nullptr && ws_size >= needKV) {
    _Float16* KH = (_Float16*)d_ws;
    _Float16* VT = KH + (size_t)NB * SL * HD;
    prep_pack_kernel<<<dim3(512), 256, 0, stream>>>(K, V, DM, MMk, KH, VT, nullptr);
    attn_kernel<1><<<grid, 512, 0, stream>>>(Q, K, V, KH, VT, nullptr, DM, MMk, Out, Attn);
  } else {
    attn_kernel<0><<<grid, 512, 0, stream>>>(Q, K, V, nullptr, nullptr, nullptr, DM, MMk, Out, Attn);
  }
}

// Round 9
// 706.329 us; speedup vs baseline: 1.0281x; 1.0281x over previous
//
#include <hip/hip_runtime.h>
#include <math.h>

#define NB 16
#define SL 2048
#define HD 64
#define TQ 32                 // round-9: 32 q-rows/block -> halves per-grid K/V traffic
#define BK 64
#define NT (SL / BK)          // 32 k-tiles
#define SC2 0.18033688f       // (1/TEMPERATURE) * log2(e): exp(s/8) = exp2(s*SC2)
#define SSTRIDE 2056          // fp16 elems per S row (2048 + 8 pad, 16B-aligned rows)

typedef _Float16 half8 __attribute__((ext_vector_type(8)));
typedef float floatx4 __attribute__((ext_vector_type(4)));
typedef int intx4 __attribute__((ext_vector_type(4)));

__device__ __forceinline__ half8 load_frag_f32(const float* p) {
  floatx4 f0 = *(const floatx4*)p;
  floatx4 f1 = *(const floatx4*)(p + 4);
  half8 h;
  h[0] = (_Float16)f0[0]; h[1] = (_Float16)f0[1];
  h[2] = (_Float16)f0[2]; h[3] = (_Float16)f0[3];
  h[4] = (_Float16)f1[0]; h[5] = (_Float16)f1[1];
  h[6] = (_Float16)f1[2]; h[7] = (_Float16)f1[3];
  return h;
}

// Fused pre-pass, 256 threads/block (unchanged — at the mask stream's BW floor).
// bid < 512  : prep — K -> KH (f16), V -> VT (f16 transposed [b][d][k]).
// bid >= 512 : pack — reads DM+MMk (537 MB), keep = dm & ~mk, bit-packed to BITS
//              (8 MiB, L2/L3-resident for the attn kernel).
__global__ __launch_bounds__(256) void prep_pack_kernel(
    const float* __restrict__ K, const float* __restrict__ V,
    const int* __restrict__ DM, const int* __restrict__ MMk,
    _Float16* __restrict__ KH, _Float16* __restrict__ VT,
    unsigned char* __restrict__ BITS)
{
  const int bid = blockIdx.x;
  const int t   = (int)threadIdx.x;

  if (bid >= 512) {
    const size_t r0 = (size_t)(bid - 512) * 16;
    #pragma unroll 4
    for (int r = 0; r < 16; ++r) {
      const size_t off = (r0 + r) * SL + (size_t)t * 8;
      intx4 d0 = __builtin_nontemporal_load((const intx4*)(DM + off));
      intx4 d1 = __builtin_nontemporal_load((const intx4*)(DM + off + 4));
      intx4 m0 = __builtin_nontemporal_load((const intx4*)(MMk + off));
      intx4 m1 = __builtin_nontemporal_load((const intx4*)(MMk + off + 4));
      unsigned byte = 0;
      #pragma unroll
      for (int j = 0; j < 4; ++j) {
        byte |= (unsigned)((d0[j] & ~m0[j]) & 1) << j;
        byte |= (unsigned)((d1[j] & ~m1[j]) & 1) << (j + 4);
      }
      BITS[(r0 + r) * (SL / 8) + t] = (unsigned char)byte;
    }
    return;
  }

  __shared__ __align__(16) _Float16 tile[64][72];   // V tile, 16-chunk XOR swizzle
  const int k0 = (bid & 31) * 64;
  const int b  = bid >> 5;
  const size_t base = (size_t)b * SL * HD;
  const int r  = t >> 2;
  const int cq = (t & 3) * 16;

  const float* kp = K + base + (size_t)(k0 + r) * HD + cq;
  const float* vp = V + base + (size_t)(k0 + r) * HD + cq;
  half8 kh0 = load_frag_f32(kp), kh1 = load_frag_f32(kp + 8);
  half8 vh0 = load_frag_f32(vp), vh1 = load_frag_f32(vp + 8);

  _Float16* khp = KH + base + (size_t)(k0 + r) * HD + cq;
  *(half8*)khp       = kh0;
  *(half8*)(khp + 8) = kh1;

  const int wc = cq ^ (((r >> 4) & 3) * 16);
  *(half8*)&tile[r][wc]     = vh0;
  *(half8*)&tile[r][wc + 8] = vh1;
  __syncthreads();

  const int sx = ((cq >> 4) & 3) * 16;
  half8 o0, o1;
  #pragma unroll
  for (int i = 0; i < 8; ++i) {
    o0[i] = tile[cq + i][r ^ sx];
    o1[i] = tile[cq + 8 + i][r ^ sx];
  }
  _Float16* vt = VT + (size_t)b * HD * SL + (size_t)r * SL + k0 + cq;
  *(half8*)vt       = o0;
  *(half8*)(vt + 8) = o1;
}

// One block = 32 q-rows of one batch, 512 threads = 8 waves, 1 block/CU (LDS 148 KB).
// Round-9 rationale: per-block KH/VT read is a CONSTANT 512 KB (full K+V scan per
// batch), so operand traffic scales with block count. R5 measured the dose-response:
// TQ 16->8 doubled blocks -> attn 171->291 us. TQ=32 halves blocks (1024) -> 512 MB
// total vs 1 GB -> predicted attn ~110-125 us. Each K/V fragment also now feeds 2
// MFMAs (M-halves 0-15 and 16-31), doubling arithmetic intensity per loaded byte.
// Occupancy drops to 8 waves/CU — R5 showed occupancy is subordinate to traffic.
// MODE 2: KH/VT + BITS. MODE 1: KH/VT, masks from global. MODE 0: no workspace.
template <int MODE>
__global__ __launch_bounds__(512, 2) void attn_kernel(
    const float* __restrict__ Q, const float* __restrict__ K,
    const float* __restrict__ V, const _Float16* __restrict__ KH,
    const _Float16* __restrict__ VT, const unsigned char* __restrict__ BITS,
    const int* __restrict__ DM, const int* __restrict__ MMk,
    float* __restrict__ Out, float* __restrict__ Attn)
{
  const int qt    = blockIdx.x;          // 0..63
  const int b     = blockIdx.y;
  const int tid   = (int)threadIdx.x;
  const int w     = tid >> 6;            // wave 0..7
  const int w4    = w & 3;               // column-group within k-tile / d-group
  const int hf    = w >> 2;              // which half of the k-tiles
  const int lane  = tid & 63;
  const int quad  = lane >> 4;
  const int nl    = lane & 15;
  const int row32 = tid >> 4;            // 0..31 (row owned in softmax/store phases)
  const int ci    = tid & 15;            // 0..15 (col-chunk group within the row)

  const int qbase    = qt * TQ;
  const size_t bLD   = (size_t)b * SL * HD;
  const size_t mbase = ((size_t)b * SL + qbase) * SL;

  __shared__ __align__(16) _Float16 S[TQ * SSTRIDE];    // 131.6 KB
  __shared__ __align__(16) unsigned char bitsB[TQ * 256]; // 8 KB keep-bits
  __shared__ float sinv_s[TQ];
  __shared__ float obuf[TQ][65];                         // 8.3 KB cross-half merge

  // ---- bits preload: thread tid loads the exact 16 mask bytes its P1 slice uses
  // (row = tid>>4, bytes [ci*16, ci*16+16) of that row) as one intx4. Coalesced.
  if constexpr (MODE == 2) {
    const intx4* bp = (const intx4*)(BITS + ((size_t)b * SL + qbase) * (SL / 8));
    ((intx4*)bitsB)[tid] = bp[tid];
  }

  // ---- Q fragments: aq0/aq1 for rows qbase+nl, aq2/aq3 for rows qbase+16+nl
  half8 aq0, aq1, aq2, aq3;
  {
    const float* qp = Q + bLD + (size_t)(qbase + nl) * HD + quad * 8;
    aq0 = load_frag_f32(qp);
    aq1 = load_frag_f32(qp + 32);
    const float* qp2 = Q + bLD + (size_t)(qbase + 16 + nl) * HD + quad * 8;
    aq2 = load_frag_f32(qp2);
    aq3 = load_frag_f32(qp2 + 32);
  }

  // ===== Phase A: QK^T -> S. Each wave: 16 k-tiles x 2 M-halves (K frags reused) =====
  const int kt0 = hf * (NT / 2);
  #pragma unroll 2
  for (int kti = 0; kti < NT / 2; ++kti) {
    const int kt = kt0 + kti;
    half8 bk0, bk1;
    if constexpr (MODE >= 1) {
      const _Float16* kp = KH + bLD + (size_t)(kt * BK + w4 * 16 + nl) * HD + quad * 8;
      bk0 = *(const half8*)kp;
      bk1 = *(const half8*)(kp + 32);
    } else {
      const float* kp = K + bLD + (size_t)(kt * BK + w4 * 16 + nl) * HD + quad * 8;
      bk0 = load_frag_f32(kp);
      bk1 = load_frag_f32(kp + 32);
    }
    floatx4 acc0 = {0.f, 0.f, 0.f, 0.f};
    floatx4 acc1 = {0.f, 0.f, 0.f, 0.f};
    acc0 = __builtin_amdgcn_mfma_f32_16x16x32_f16(aq0, bk0, acc0, 0, 0, 0);
    acc0 = __builtin_amdgcn_mfma_f32_16x16x32_f16(aq1, bk1, acc0, 0, 0, 0);
    acc1 = __builtin_amdgcn_mfma_f32_16x16x32_f16(aq2, bk0, acc1, 0, 0, 0);
    acc1 = __builtin_amdgcn_mfma_f32_16x16x32_f16(aq3, bk1, acc1, 0, 0, 0);
    const int col = kt * BK + w4 * 16 + nl;
    #pragma unroll
    for (int r = 0; r < 4; ++r) {
      S[(quad * 4 + r) * SSTRIDE + col]        = (_Float16)(acc0[r] * SC2);
      S[(16 + quad * 4 + r) * SSTRIDE + col]   = (_Float16)(acc1[r] * SC2);
    }
  }
  __syncthreads();   // S + bitsB visible

  // ===== P1: row = row32, 16 threads/row; mask bits + exp2 + 16-lane sum =====
  // chunk it: cols [it*128 + ci*8, +8)  -> lanes consecutive 16B (conflict-free);
  // mask byte at bitsB[row*256 + it*16 + ci].
  _Float16* srow = &S[row32 * SSTRIDE];
  float sum = 0.f;
  if constexpr (MODE == 2) {
    #pragma unroll 4
    for (int it = 0; it < 16; ++it) {
      const int c = it * 128 + ci * 8;
      const unsigned kb = bitsB[row32 * 256 + it * 16 + ci];
      half8 s8 = *(const half8*)(srow + c);
      half8 e8;
      #pragma unroll
      for (int j = 0; j < 4; ++j) {
        const float e0 = (kb & (1u << j))       ? __builtin_amdgcn_exp2f((float)s8[j])     : 0.f;
        const float e1 = (kb & (1u << (j + 4))) ? __builtin_amdgcn_exp2f((float)s8[j + 4]) : 0.f;
        sum += e0 + e1;
        e8[j]     = (_Float16)e0;   // e <= ~e^6, fp16 safe (validated earlier rounds)
        e8[j + 4] = (_Float16)e1;
      }
      *(half8*)(srow + c) = e8;     // unnormalized e for PV
    }
  } else {
    const int* dmr = DM  + mbase + (size_t)row32 * SL;
    const int* mkr = MMk + mbase + (size_t)row32 * SL;
    #pragma unroll 4
    for (int it = 0; it < 16; ++it) {
      const int c = it * 128 + ci * 8;
      intx4 d0 = __builtin_nontemporal_load((const intx4*)(dmr + c));
      intx4 d1 = __builtin_nontemporal_load((const intx4*)(dmr + c + 4));
      intx4 m0 = __builtin_nontemporal_load((const intx4*)(mkr + c));
      intx4 m1 = __builtin_nontemporal_load((const intx4*)(mkr + c + 4));
      half8 s8 = *(const half8*)(srow + c);
      half8 e8;
      #pragma unroll
      for (int j = 0; j < 4; ++j) {
        const int keep0 = d0[j] & ~m0[j];
        const int keep1 = d1[j] & ~m1[j];
        const float e0 = keep0 ? __builtin_amdgcn_exp2f((float)s8[j])     : 0.f;
        const float e1 = keep1 ? __builtin_amdgcn_exp2f((float)s8[j + 4]) : 0.f;
        sum += e0 + e1;
        e8[j]     = (_Float16)e0;
        e8[j + 4] = (_Float16)e1;
      }
      *(half8*)(srow + c) = e8;
    }
  }
  #pragma unroll
  for (int off = 1; off < 16; off <<= 1)
    sum += __shfl_xor(sum, off, 64);   // 16 chunk-lanes of this row
  if (ci == 0) sinv_s[row32] = (sum > 0.f) ? 1.f / sum : 0.f;
  __syncthreads();   // all e in S + sinv_s visible before PV

  // ===== PV MFMA: 16 tiles/wave x 2 M-halves (V frags reused), with =====
  // ===== one interleaved normalized attn store chunk per tile        =====
  const float isr = sinv_s[row32];
  float* arow = Attn + mbase + (size_t)row32 * SL;
  floatx4 oacc0 = {0.f, 0.f, 0.f, 0.f};
  floatx4 oacc1 = {0.f, 0.f, 0.f, 0.f};
  #pragma unroll 2
  for (int kti = 0; kti < NT / 2; ++kti) {
    const int kt = kt0 + kti;
    // A operands: rows nl (low half) and 16+nl (high half)
    half8 ap0 = *(const half8*)(&S[nl * SSTRIDE + kt * BK + quad * 8]);
    half8 ap1 = *(const half8*)(&S[nl * SSTRIDE + kt * BK + quad * 8 + 32]);
    half8 ap2 = *(const half8*)(&S[(16 + nl) * SSTRIDE + kt * BK + quad * 8]);
    half8 ap3 = *(const half8*)(&S[(16 + nl) * SSTRIDE + kt * BK + quad * 8 + 32]);
    // B operand: lane holds V[k = kt*64 + quad*8 + j (+32)][n = w4*16 + nl]
    half8 bv0, bv1;
    if constexpr (MODE >= 1) {
      const _Float16* vp = VT + bLD + (size_t)(w4 * 16 + nl) * SL + kt * BK + quad * 8;
      bv0 = *(const half8*)vp;
      bv1 = *(const half8*)(vp + 32);
    } else {
      const float* vp = V + bLD + (size_t)(kt * BK + quad * 8) * HD + w4 * 16 + nl;
      #pragma unroll
      for (int j = 0; j < 8; ++j) {
        bv0[j] = (_Float16)vp[(size_t)j * HD];
        bv1[j] = (_Float16)vp[(size_t)(j + 32) * HD];
      }
    }
    oacc0 = __builtin_amdgcn_mfma_f32_16x16x32_f16(ap0, bv0, oacc0, 0, 0, 0);
    oacc0 = __builtin_amdgcn_mfma_f32_16x16x32_f16(ap1, bv1, oacc0, 0, 0, 0);
    oacc1 = __builtin_amdgcn_mfma_f32_16x16x32_f16(ap2, bv0, oacc1, 0, 0, 0);
    oacc1 = __builtin_amdgcn_mfma_f32_16x16x32_f16(ap3, bv1, oacc1, 0, 0, 0);
    // normalized attn store: chunk kti of this thread's row (16 chunks over 16 tiles)
    {
      const int c = kti * 128 + ci * 8;
      half8 e8v = *(const half8*)(srow + c);
      floatx4 o0, o1;
      #pragma unroll
      for (int j = 0; j < 4; ++j) {
        o0[j] = (float)e8v[j]     * isr;
        o1[j] = (float)e8v[j + 4] * isr;
      }
      __builtin_nontemporal_store(o0, (floatx4*)(arow + c));
      __builtin_nontemporal_store(o1, (floatx4*)(arow + c + 4));
    }
  }

  // ---- merge the two k-halves, normalize, store O (rows 0..31)
  if (hf == 1) {
    #pragma unroll
    for (int r = 0; r < 4; ++r) {
      obuf[quad * 4 + r][w4 * 16 + nl]      = oacc0[r];
      obuf[16 + quad * 4 + r][w4 * 16 + nl] = oacc1[r];
    }
  }
  __syncthreads();
  if (hf == 0) {
    float* op = Out + ((size_t)b * SL + qbase) * HD;
    #pragma unroll
    for (int r = 0; r < 4; ++r) {
      const int row = quad * 4 + r;
      op[(size_t)row * HD + w4 * 16 + nl] =
          (oacc0[r] + obuf[row][w4 * 16 + nl]) * sinv_s[row];
      const int row2 = 16 + quad * 4 + r;
      op[(size_t)row2 * HD + w4 * 16 + nl] =
          (oacc1[r] + obuf[row2][w4 * 16 + nl]) * sinv_s[row2];
    }
  }
}

extern "C" void kernel_launch(void* const* d_in, const int* in_sizes, int n_in,
                              void* d_out, int out_size, void* d_ws, size_t ws_size,
                              hipStream_t stream) {
  const float* Q  = (const float*)d_in[0];
  const float* K  = (const float*)d_in[1];
  const float* V  = (const float*)d_in[2];
  const int* DM   = (const int*)d_in[3];
  const int* MMk  = (const int*)d_in[4];
  float* Out  = (float*)d_out;
  float* Attn = (float*)d_out + (size_t)NB * SL * HD;
  dim3 grid(SL / TQ, NB);   // 64 x 16 = 1024 blocks

  const size_t needKV   = (size_t)2 * NB * SL * HD * sizeof(_Float16);  // 8 MiB
  const size_t needBits = (size_t)NB * SL * (SL / 8);                   // 8 MiB
  if (d_ws != nullptr && ws_size >= needKV + needBits) {
    _Float16* KH = (_Float16*)d_ws;
    _Float16* VT = KH + (size_t)NB * SL * HD;
    unsigned char* BITS = (unsigned char*)(VT + (size_t)NB * SL * HD);
    prep_pack_kernel<<<dim3(512 + 2048), 256, 0, stream>>>(K, V, DM, MMk, KH, VT, BITS);
    attn_kernel<2><<<grid, 512, 0, stream>>>(Q, K, V, KH, VT, BITS, DM, MMk, Out, Attn);
  } else if (d_ws != nullptr && ws_size >= needKV) {
    _Float16* KH = (_Float16*)d_ws;
    _Float16* VT = KH + (size_t)NB * SL * HD;
    prep_pack_kernel<<<dim3(512), 256, 0, stream>>>(K, V, DM, MMk, KH, VT, nullptr);
    attn_kernel<1><<<grid, 512, 0, stream>>>(Q, K, V, KH, VT, nullptr, DM, MMk, Out, Attn);
  } else {
    attn_kernel<0><<<grid, 512, 0, stream>>>(Q, K, V, nullptr, nullptr, nullptr, DM, MMk, Out, Attn);
  }
}